// Round 1
// baseline (338.766 us; speedup 1.0000x reference)
//
#include <hip/hip_runtime.h>
#include <hip/hip_bf16.h>
#include <math.h>

#define N_SPECIES 4
#define NNZ       16384
#define MPS       4096      // NNZ / N_SPECIES (rows per species in z/batch_idx)
#define N_CELLS   512
#define N_LATENT  256
#define HDIM      1024
#define N_GENES   20000

typedef __bf16 bf16x8 __attribute__((ext_vector_type(8)));
typedef float  f32x4  __attribute__((ext_vector_type(4)));

static __device__ __forceinline__ unsigned short f2b(float f) {
    __hip_bfloat16 h = __float2bfloat16(f);
    return __builtin_bit_cast(unsigned short, h);
}

// ---------------------------------------------------------------------------
// Kernel 1: transpose + convert W (S, K, N) f32  ->  Wt (S, N, K) bf16
// ---------------------------------------------------------------------------
__global__ __launch_bounds__(256) void transpose_bf16(
    const float* __restrict__ W, unsigned short* __restrict__ Wt, int K, int N)
{
    __shared__ float tile[32][33];
    int s = blockIdx.z;
    const float* Ws = W + (size_t)s * K * N;
    unsigned short* Wts = Wt + (size_t)s * N * K;
    int n0 = blockIdx.x * 32, k0 = blockIdx.y * 32;
    int tx = threadIdx.x, ty = threadIdx.y;   // block (32, 8)
    #pragma unroll
    for (int p = 0; p < 4; p++)
        tile[ty + 8 * p][tx] = Ws[(size_t)(k0 + ty + 8 * p) * N + n0 + tx];
    __syncthreads();
    #pragma unroll
    for (int p = 0; p < 4; p++) {
        int r = ty + 8 * p;                   // n offset within tile
        Wts[(size_t)(n0 + r) * K + k0 + tx] = f2b(tile[tx][r]);
    }
}

// ---------------------------------------------------------------------------
// Kernel 2: build combined input  A (S, 512, 512) bf16
//           A[s][r][0:256]   = z[s][r][:]
//           A[s][r][256:512] = global_latent[batch_idx[s*4096 + r]][:]
// ---------------------------------------------------------------------------
__global__ __launch_bounds__(256) void build_combined(
    const float* __restrict__ z, const float* __restrict__ gl,
    const int* __restrict__ bidx, unsigned short* __restrict__ A)
{
    int idx = blockIdx.x * 256 + threadIdx.x;      // over 4*512*512 elements
    int c = idx & 511;
    int r = (idx >> 9) & 511;
    int s = idx >> 18;
    float v;
    if (c < N_LATENT)
        v = z[((size_t)s * MPS + r) * N_LATENT + c];
    else
        v = gl[(size_t)bidx[s * MPS + r] * N_LATENT + (c - N_LATENT)];
    A[idx] = f2b(v);
}

// ---------------------------------------------------------------------------
// Kernel 3: bf16 MFMA GEMM:  C = relu(A @ B + bias)
//   A  (S, M, K) bf16 row-major
//   Bt (S, N, K) bf16 (n-major, i.e. B transposed)
//   out: bf16 (ushort) or f32 per flag
// Tile: BM=BN=64, BK=64, 256 threads = 4 waves (2x2), wave = 32x32 out
// LDS layout: [64 rows][8 kblocks of 8 bf16], phys_kblk = kblk ^ (row & 7)
// mfma_f32_16x16x32_bf16; D mapping (verified m89): col=lane&15, row=(lane>>4)*4+reg
// ---------------------------------------------------------------------------
__global__ __launch_bounds__(256) void gemm_bf16_mfma(
    const unsigned short* __restrict__ A, const unsigned short* __restrict__ Bt,
    const float* __restrict__ bias, void* __restrict__ Cptr,
    int M, int N, int K, int out_bf16)
{
    int s = blockIdx.z;
    const unsigned short* As = A  + (size_t)s * M * K;
    const unsigned short* Bs = Bt + (size_t)s * N * K;
    const float* bvec = bias + (size_t)s * N;

    int m0 = blockIdx.x * 64, n0 = blockIdx.y * 64;

    __shared__ unsigned short Alds[64 * 64];
    __shared__ unsigned short Blds[64 * 64];

    int tid  = threadIdx.x;
    int lane = tid & 63, w = tid >> 6;
    int wr = w >> 1, wc = w & 1;

    f32x4 acc[2][2] = {};

    for (int kt = 0; kt < K; kt += 64) {
        // ---- stage 64x64 A and B tiles (16B chunks, XOR-swizzled kblocks)
        #pragma unroll
        for (int it = 0; it < 2; it++) {
            int c   = it * 256 + tid;         // chunk id 0..511
            int row = c >> 3, kb = c & 7;
            int pa  = kb ^ (row & 7);
            uint4 va = *(const uint4*)(As + (size_t)(m0 + row) * K + kt + kb * 8);
            *(uint4*)(Alds + row * 64 + pa * 8) = va;
            uint4 vb = *(const uint4*)(Bs + (size_t)(n0 + row) * K + kt + kb * 8);
            *(uint4*)(Blds + row * 64 + pa * 8) = vb;
        }
        __syncthreads();
        // ---- compute: 2 mfma-K substeps of 32
        #pragma unroll
        for (int ks = 0; ks < 2; ks++) {
            bf16x8 af[2], bfr[2];
            #pragma unroll
            for (int f = 0; f < 2; f++) {
                int ar  = wr * 32 + f * 16 + (lane & 15);
                int akb = (ks * 4 + (lane >> 4)) ^ (ar & 7);
                af[f]  = __builtin_bit_cast(bf16x8, *(const uint4*)(Alds + ar * 64 + akb * 8));
                int br  = wc * 32 + f * 16 + (lane & 15);
                int bkb = (ks * 4 + (lane >> 4)) ^ (br & 7);
                bfr[f] = __builtin_bit_cast(bf16x8, *(const uint4*)(Blds + br * 64 + bkb * 8));
            }
            #pragma unroll
            for (int fm = 0; fm < 2; fm++)
                #pragma unroll
                for (int fn = 0; fn < 2; fn++)
                    acc[fm][fn] = __builtin_amdgcn_mfma_f32_16x16x32_bf16(
                        af[fm], bfr[fn], acc[fm][fn], 0, 0, 0);
        }
        __syncthreads();
    }

    // ---- epilogue: bias + relu + store
    #pragma unroll
    for (int fm = 0; fm < 2; fm++)
        #pragma unroll
        for (int fn = 0; fn < 2; fn++) {
            int col = n0 + wc * 32 + fn * 16 + (lane & 15);
            float bv = bvec[col];
            #pragma unroll
            for (int r = 0; r < 4; r++) {
                int row = m0 + wr * 32 + fm * 16 + (lane >> 4) * 4 + r;
                float v = acc[fm][fn][r] + bv;
                v = fmaxf(v, 0.0f);
                size_t off = (size_t)s * M * N + (size_t)row * N + col;
                if (out_bf16) ((unsigned short*)Cptr)[off] = f2b(v);
                else          ((float*)Cptr)[off] = v;
            }
        }
}

// ---------------------------------------------------------------------------
// Kernel 4: per-entry gather-dot decode
//   out[j] = softplus( dot(H2[s][bi[j]], W3[s][:,gi[j]]) + b3[s][gi[j]] )
// one wave per entry j
// ---------------------------------------------------------------------------
__global__ __launch_bounds__(256) void gather_decode(
    const float* __restrict__ H2, const int* __restrict__ bidx,
    const int* __restrict__ gidx, const float* __restrict__ W3,
    const float* __restrict__ b3, float* __restrict__ out)
{
    int j    = blockIdx.x * 4 + (threadIdx.x >> 6);
    int lane = threadIdx.x & 63;
    int s  = j >> 12;                       // j / 4096
    int bi = bidx[j], gi = gidx[j];
    const float* h = H2 + ((size_t)s * N_CELLS + bi) * HDIM;
    const float* wcol = W3 + (size_t)s * HDIM * N_GENES + gi;
    float sum = 0.f;
    #pragma unroll
    for (int t = 0; t < HDIM / 64; t++) {
        int hh = t * 64 + lane;
        sum += h[hh] * wcol[(size_t)hh * N_GENES];
    }
    #pragma unroll
    for (int off = 32; off; off >>= 1)
        sum += __shfl_xor(sum, off, 64);
    if (lane == 0) {
        float x = sum + b3[(size_t)s * N_GENES + gi];
        out[j] = (x > 20.f) ? x : log1pf(expf(x));
    }
}

// ---------------------------------------------------------------------------
extern "C" void kernel_launch(void* const* d_in, const int* in_sizes, int n_in,
                              void* d_out, int out_size, void* d_ws, size_t ws_size,
                              hipStream_t stream) {
    // inputs (setup_inputs order)
    const int*   batch_idx = (const int*)  d_in[1];
    const int*   gene_idx  = (const int*)  d_in[2];
    const float* gl        = (const float*)d_in[3];
    const float* z         = (const float*)d_in[4];
    const float* W1        = (const float*)d_in[5];
    const float* b1        = (const float*)d_in[6];
    const float* W2        = (const float*)d_in[7];
    const float* b2        = (const float*)d_in[8];
    const float* W3        = (const float*)d_in[9];
    const float* b3        = (const float*)d_in[10];
    float* out = (float*)d_out;

    char* ws = (char*)d_ws;
    unsigned short* Wt1  = (unsigned short*)(ws + 0);                 //  4 MB (4,1024,512) bf16
    unsigned short* Wt2  = (unsigned short*)(ws + (4ull  << 20));     //  8 MB (4,1024,1024) bf16
    unsigned short* Acmb = (unsigned short*)(ws + (12ull << 20));     //  2 MB (4,512,512)  bf16
    unsigned short* H1   = (unsigned short*)(ws + (14ull << 20));     //  4 MB (4,512,1024) bf16
    float*          H2   = (float*)        (ws + (18ull << 20));      //  8 MB (4,512,1024) f32

    // 1) weight transposes (f32 -> bf16, n-major)
    transpose_bf16<<<dim3(HDIM / 32, (2 * N_LATENT) / 32, N_SPECIES), dim3(32, 8), 0, stream>>>(
        W1, Wt1, 2 * N_LATENT, HDIM);
    transpose_bf16<<<dim3(HDIM / 32, HDIM / 32, N_SPECIES), dim3(32, 8), 0, stream>>>(
        W2, Wt2, HDIM, HDIM);

    // 2) combined input (concat z rows with gathered global latent)
    build_combined<<<(N_SPECIES * N_CELLS * 2 * N_LATENT) / 256, 256, 0, stream>>>(
        z, gl, batch_idx, Acmb);

    // 3) layer 1: H1 = relu(Acmb @ W1 + b1)   M=512 K=512 N=1024, bf16 out
    gemm_bf16_mfma<<<dim3(N_CELLS / 64, HDIM / 64, N_SPECIES), 256, 0, stream>>>(
        Acmb, Wt1, b1, H1, N_CELLS, HDIM, 2 * N_LATENT, 1);

    // 4) layer 2: H2 = relu(H1 @ W2 + b2)     M=512 K=1024 N=1024, f32 out
    gemm_bf16_mfma<<<dim3(N_CELLS / 64, HDIM / 64, N_SPECIES), 256, 0, stream>>>(
        H1, Wt2, b2, H2, N_CELLS, HDIM, HDIM, 0);

    // 5) gather-dot over W3 columns + softplus
    gather_decode<<<NNZ / 4, 256, 0, stream>>>(H2, batch_idx, gene_idx, W3, b3, out);
}

// Round 2
// 151.235 us; speedup vs baseline: 2.2400x; 2.2400x over previous
//
#include <hip/hip_runtime.h>
#include <hip/hip_bf16.h>
#include <math.h>

#define N_SPECIES 4
#define NNZ       16384
#define MPS       4096      // NNZ / N_SPECIES (rows per species in z/batch_idx)
#define N_CELLS   512
#define N_LATENT  256
#define HDIM      1024
#define N_GENES   20000

typedef __bf16 bf16x8 __attribute__((ext_vector_type(8)));
typedef float  f32x4  __attribute__((ext_vector_type(4)));

static __device__ __forceinline__ unsigned short f2b(float f) {
    __hip_bfloat16 h = __float2bfloat16(f);
    return __builtin_bit_cast(unsigned short, h);
}
static __device__ __forceinline__ float b2f_lo(unsigned int u) {
    return __builtin_bit_cast(float, u << 16);
}
static __device__ __forceinline__ float b2f_hi(unsigned int u) {
    return __builtin_bit_cast(float, u & 0xffff0000u);
}

// ---------------------------------------------------------------------------
// Kernel 1: transpose + convert W (S, K, N) f32  ->  Wt (S, N, K) bf16
// (used for W1, W2 — small)
// ---------------------------------------------------------------------------
__global__ __launch_bounds__(256) void transpose_bf16(
    const float* __restrict__ W, unsigned short* __restrict__ Wt, int K, int N)
{
    __shared__ float tile[32][33];
    int s = blockIdx.z;
    const float* Ws = W + (size_t)s * K * N;
    unsigned short* Wts = Wt + (size_t)s * N * K;
    int n0 = blockIdx.x * 32, k0 = blockIdx.y * 32;
    int tx = threadIdx.x, ty = threadIdx.y;   // block (32, 8)
    #pragma unroll
    for (int p = 0; p < 4; p++)
        tile[ty + 8 * p][tx] = Ws[(size_t)(k0 + ty + 8 * p) * N + n0 + tx];
    __syncthreads();
    #pragma unroll
    for (int p = 0; p < 4; p++) {
        int r = ty + 8 * p;                   // n offset within tile
        Wts[(size_t)(n0 + r) * K + k0 + tx] = f2b(tile[tx][r]);
    }
}

// ---------------------------------------------------------------------------
// Kernel 1b: W3 transpose + convert  (S, H=1024, G=20000) f32 -> (S, G, H) bf16
// tile: 64 k-rows x 32 genes. float4 coalesced loads (128B/row-segment),
// uint4 bf16 stores (128B per 8 lanes). LDS pad 33 -> max 2-way bank alias.
// ---------------------------------------------------------------------------
__global__ __launch_bounds__(256) void transpose_w3(
    const float* __restrict__ W, unsigned short* __restrict__ Wt)
{
    __shared__ float tile[64][33];            // [k_local][g_local]
    int s  = blockIdx.z;
    int g0 = blockIdx.x * 32;
    int k0 = blockIdx.y * 64;
    const float* Ws = W + (size_t)s * HDIM * N_GENES;
    unsigned short* Wts = Wt + (size_t)s * N_GENES * HDIM;
    int tid = threadIdx.x;

    int lr = tid >> 3, lc = (tid & 7) * 4;    // 32 rows/pass, 8 lanes x float4
    #pragma unroll
    for (int p = 0; p < 2; p++) {
        int kl = lr + p * 32;
        float4 v = *(const float4*)(Ws + (size_t)(k0 + kl) * N_GENES + g0 + lc);
        tile[kl][lc]     = v.x;
        tile[kl][lc + 1] = v.y;
        tile[kl][lc + 2] = v.z;
        tile[kl][lc + 3] = v.w;
    }
    __syncthreads();

    int g = tid >> 3, kc = (tid & 7) * 8;     // 32 genes, 8 lanes x 8 bf16
    unsigned short o[8];
    #pragma unroll
    for (int i = 0; i < 8; i++) o[i] = f2b(tile[kc + i][g]);
    *(uint4*)(Wts + (size_t)(g0 + g) * HDIM + k0 + kc) = *(const uint4*)o;
}

// ---------------------------------------------------------------------------
// Kernel 2: build combined input  A (S, 512, 512) bf16
// ---------------------------------------------------------------------------
__global__ __launch_bounds__(256) void build_combined(
    const float* __restrict__ z, const float* __restrict__ gl,
    const int* __restrict__ bidx, unsigned short* __restrict__ A)
{
    int idx = blockIdx.x * 256 + threadIdx.x;      // over 4*512*512 elements
    int c = idx & 511;
    int r = (idx >> 9) & 511;
    int s = idx >> 18;
    float v;
    if (c < N_LATENT)
        v = z[((size_t)s * MPS + r) * N_LATENT + c];
    else
        v = gl[(size_t)bidx[s * MPS + r] * N_LATENT + (c - N_LATENT)];
    A[idx] = f2b(v);
}

// ---------------------------------------------------------------------------
// Kernel 3: bf16 MFMA GEMM:  C = relu(A @ B + bias)
//   A  (S, M, K) bf16 row-major, Bt (S, N, K) bf16 n-major
// Tile BM=BN=64, BK=64, 4 waves (2x2), wave = 32x32 out, XOR-swizzled LDS
// D mapping (m89): col=lane&15, row=(lane>>4)*4+reg
// ---------------------------------------------------------------------------
__global__ __launch_bounds__(256) void gemm_bf16_mfma(
    const unsigned short* __restrict__ A, const unsigned short* __restrict__ Bt,
    const float* __restrict__ bias, void* __restrict__ Cptr,
    int M, int N, int K, int out_bf16)
{
    int s = blockIdx.z;
    const unsigned short* As = A  + (size_t)s * M * K;
    const unsigned short* Bs = Bt + (size_t)s * N * K;
    const float* bvec = bias + (size_t)s * N;

    int m0 = blockIdx.x * 64, n0 = blockIdx.y * 64;

    __shared__ unsigned short Alds[64 * 64];
    __shared__ unsigned short Blds[64 * 64];

    int tid  = threadIdx.x;
    int lane = tid & 63, w = tid >> 6;
    int wr = w >> 1, wc = w & 1;

    f32x4 acc[2][2] = {};

    for (int kt = 0; kt < K; kt += 64) {
        #pragma unroll
        for (int it = 0; it < 2; it++) {
            int c   = it * 256 + tid;
            int row = c >> 3, kb = c & 7;
            int pa  = kb ^ (row & 7);
            uint4 va = *(const uint4*)(As + (size_t)(m0 + row) * K + kt + kb * 8);
            *(uint4*)(Alds + row * 64 + pa * 8) = va;
            uint4 vb = *(const uint4*)(Bs + (size_t)(n0 + row) * K + kt + kb * 8);
            *(uint4*)(Blds + row * 64 + pa * 8) = vb;
        }
        __syncthreads();
        #pragma unroll
        for (int ks = 0; ks < 2; ks++) {
            bf16x8 af[2], bfr[2];
            #pragma unroll
            for (int f = 0; f < 2; f++) {
                int ar  = wr * 32 + f * 16 + (lane & 15);
                int akb = (ks * 4 + (lane >> 4)) ^ (ar & 7);
                af[f]  = __builtin_bit_cast(bf16x8, *(const uint4*)(Alds + ar * 64 + akb * 8));
                int br  = wc * 32 + f * 16 + (lane & 15);
                int bkb = (ks * 4 + (lane >> 4)) ^ (br & 7);
                bfr[f] = __builtin_bit_cast(bf16x8, *(const uint4*)(Blds + br * 64 + bkb * 8));
            }
            #pragma unroll
            for (int fm = 0; fm < 2; fm++)
                #pragma unroll
                for (int fn = 0; fn < 2; fn++)
                    acc[fm][fn] = __builtin_amdgcn_mfma_f32_16x16x32_bf16(
                        af[fm], bfr[fn], acc[fm][fn], 0, 0, 0);
        }
        __syncthreads();
    }

    #pragma unroll
    for (int fm = 0; fm < 2; fm++)
        #pragma unroll
        for (int fn = 0; fn < 2; fn++) {
            int col = n0 + wc * 32 + fn * 16 + (lane & 15);
            float bv = bvec[col];
            #pragma unroll
            for (int r = 0; r < 4; r++) {
                int row = m0 + wr * 32 + fm * 16 + (lane >> 4) * 4 + r;
                float v = acc[fm][fn][r] + bv;
                v = fmaxf(v, 0.0f);
                size_t off = (size_t)s * M * N + (size_t)row * N + col;
                if (out_bf16) ((unsigned short*)Cptr)[off] = f2b(v);
                else          ((float*)Cptr)[off] = v;
            }
        }
}

// ---------------------------------------------------------------------------
// Kernel 4: per-entry gather-dot decode (coalesced W3t rows)
//   out[j] = softplus( dot(H2[s][bi[j]], W3t[s][gi[j]][:]) + b3[s][gi[j]] )
// one wave per entry, 16 bf16 (32B) per lane, contiguous 2KB per wave
// ---------------------------------------------------------------------------
__global__ __launch_bounds__(256) void gather_decode(
    const float* __restrict__ H2, const int* __restrict__ bidx,
    const int* __restrict__ gidx, const unsigned short* __restrict__ W3t,
    const float* __restrict__ b3, float* __restrict__ out)
{
    int j    = blockIdx.x * 4 + (threadIdx.x >> 6);
    int lane = threadIdx.x & 63;
    int s  = j >> 12;                       // j / 4096
    int bi = bidx[j], gi = gidx[j];
    const float*          h = H2  + ((size_t)s * N_CELLS + bi) * HDIM + lane * 16;
    const unsigned short* w = W3t + ((size_t)s * N_GENES + gi) * HDIM + lane * 16;

    float sum = 0.f;
    #pragma unroll
    for (int t = 0; t < 2; t++) {
        uint4  wq = *(const uint4*)(w + t * 8);
        float4 h0 = *(const float4*)(h + t * 8);
        float4 h1 = *(const float4*)(h + t * 8 + 4);
        sum += b2f_lo(wq.x) * h0.x + b2f_hi(wq.x) * h0.y;
        sum += b2f_lo(wq.y) * h0.z + b2f_hi(wq.y) * h0.w;
        sum += b2f_lo(wq.z) * h1.x + b2f_hi(wq.z) * h1.y;
        sum += b2f_lo(wq.w) * h1.z + b2f_hi(wq.w) * h1.w;
    }
    #pragma unroll
    for (int off = 32; off; off >>= 1)
        sum += __shfl_xor(sum, off, 64);
    if (lane == 0) {
        float x = sum + b3[(size_t)s * N_GENES + gi];
        out[j] = (x > 20.f) ? x : log1pf(expf(x));
    }
}

// ---------------------------------------------------------------------------
extern "C" void kernel_launch(void* const* d_in, const int* in_sizes, int n_in,
                              void* d_out, int out_size, void* d_ws, size_t ws_size,
                              hipStream_t stream) {
    const int*   batch_idx = (const int*)  d_in[1];
    const int*   gene_idx  = (const int*)  d_in[2];
    const float* gl        = (const float*)d_in[3];
    const float* z         = (const float*)d_in[4];
    const float* W1        = (const float*)d_in[5];
    const float* b1        = (const float*)d_in[6];
    const float* W2        = (const float*)d_in[7];
    const float* b2        = (const float*)d_in[8];
    const float* W3        = (const float*)d_in[9];
    const float* b3        = (const float*)d_in[10];
    float* out = (float*)d_out;

    char* ws = (char*)d_ws;
    unsigned short* Wt1  = (unsigned short*)(ws + 0);                 //  4 MB (4,1024,512)  bf16
    unsigned short* Wt2  = (unsigned short*)(ws + (4ull  << 20));     //  8 MB (4,1024,1024) bf16
    unsigned short* Acmb = (unsigned short*)(ws + (12ull << 20));     //  2 MB (4,512,512)   bf16
    unsigned short* H1   = (unsigned short*)(ws + (14ull << 20));     //  4 MB (4,512,1024)  bf16
    float*          H2   = (float*)        (ws + (18ull << 20));      //  8 MB (4,512,1024)  f32
    unsigned short* W3t  = (unsigned short*)(ws + (26ull << 20));     // 164 MB (4,20000,1024) bf16

    // 1) weight transposes (f32 -> bf16, n-major)
    transpose_bf16<<<dim3(HDIM / 32, (2 * N_LATENT) / 32, N_SPECIES), dim3(32, 8), 0, stream>>>(
        W1, Wt1, 2 * N_LATENT, HDIM);
    transpose_bf16<<<dim3(HDIM / 32, HDIM / 32, N_SPECIES), dim3(32, 8), 0, stream>>>(
        W2, Wt2, HDIM, HDIM);
    transpose_w3<<<dim3(N_GENES / 32, HDIM / 64, N_SPECIES), 256, 0, stream>>>(W3, W3t);

    // 2) combined input (concat z rows with gathered global latent)
    build_combined<<<(N_SPECIES * N_CELLS * 2 * N_LATENT) / 256, 256, 0, stream>>>(
        z, gl, batch_idx, Acmb);

    // 3) layer 1: H1 = relu(Acmb @ W1 + b1)   M=512 K=512 N=1024, bf16 out
    gemm_bf16_mfma<<<dim3(N_CELLS / 64, HDIM / 64, N_SPECIES), 256, 0, stream>>>(
        Acmb, Wt1, b1, H1, N_CELLS, HDIM, 2 * N_LATENT, 1);

    // 4) layer 2: H2 = relu(H1 @ W2 + b2)     M=512 K=1024 N=1024, f32 out
    gemm_bf16_mfma<<<dim3(N_CELLS / 64, HDIM / 64, N_SPECIES), 256, 0, stream>>>(
        H1, Wt2, b2, H2, N_CELLS, HDIM, HDIM, 0);

    // 5) coalesced gather-dot over W3t rows + softplus
    gather_decode<<<NNZ / 4, 256, 0, stream>>>(H2, batch_idx, gene_idx, W3t, b3, out);
}